// Round 17
// baseline (64.241 us; speedup 1.0000x reference)
//
#include <hip/hip_runtime.h>
#include <math.h>

#define D_MODEL 2048
#define NE      64
#define TB      64               // tokens per fused block
#define KC      64               // fp32 k per chunk
#define NCH     (D_MODEL / KC)   // 32 chunks (KS=1)
#define FB_KC   32
#define FB_NCH  (D_MODEL / FB_KC)

typedef _Float16 half8 __attribute__((ext_vector_type(8)));
typedef float    f32x4 __attribute__((ext_vector_type(4)));

// two-term split of one float into fp16 high+low at ext-vector slot J.
// Named vars + constant indices only (rule #20 — unions/arrays → scratch).
#define CVT1(F, HV, LV, J) do {                                               \
    float _f = (F);                                                           \
    _Float16 _h = (_Float16)_f;                                               \
    HV[J] = _h;                                                               \
    LV[J] = (_Float16)(_f - (float)_h);                                       \
} while (0)

// ---------------- fused MFMA gemm + stats, 256 thr, 64KB -> 2 blocks/CU -----
// logits*512 = (8x)(64w) = 4 mfma/k-step (r11-16 proven). NEW vs r16:
// (1) 64KB LDS (2x32KB dbuf) -> 2 independent blocks/CU: cross-block TLP
//     fills each block's lgkm-drain+barrier (r16 had 1 block/CU: convoy).
// (2) W converted in-block from original fp32 W (same bytes, L2-cached,
//     bit-identical CVT1) -> wcvt kernel + launch eliminated.
// Chain: k ascending, KS=1 (r13-proven absmax 4.88e-4).
__global__ __launch_bounds__(256, 2) void router_fused_v2(
    const float* __restrict__ x, const float* __restrict__ W,
    float* __restrict__ out, float* __restrict__ ws_prob,
    float* __restrict__ ws_z, int* __restrict__ ws_cnt, int Ntok)
{
    __shared__ __align__(16) char smem[65536];    // 2 bufs x 32KB

    const int t  = threadIdx.x;
    const int b  = blockIdx.x;
    const int m0 = b * TB;
    const int l  = t & 63;
    const int wv = t >> 6;                   // 0..3

    // buf bb -> smem + bb*32768; within: Ah@0 Al@8K Wh@16K Wl@24K (64-half rows)
    // stats region (aliases smem after loop)
    float (*sL)[NE + 1] = (float (*)[NE + 1])smem;            // 16640 B
    float (*red4)[4]    = (float (*)[4])(smem + 20480);       // 1 KB
    int   (*arg4)[4]    = (int (*)[4])(smem + 24576);         // 1 KB
    float* smax         = (float*)(smem + 28672);
    float* sinv         = (float*)(smem + 28928);
    float (*spart)[NE]  = (float (*)[NE])(smem + 29184);      // 1 KB
    int*   hist         = (int*)(smem + 30720);

    // staging map (r16-proven): srow = row 0..63 (token for A / expert for W),
    // sc = 16-float col group; swizzled 16B slot = (sc*2+j) ^ (srow&7)
    const int srow = t >> 2;
    const int sc   = t & 3;
    const int ssw  = srow & 7;
    const int sof0 = (srow << 6) + (((sc * 2 + 0) ^ ssw) << 3);  // halves
    const int sof1 = (srow << 6) + (((sc * 2 + 1) ^ ssw) << 3);

    float4 aA0, aA1, aA2, aA3;               // A set even (16 fp32)
    float4 aB0, aB1, aB2, aB3;               // A set odd
    float4 wA0, wA1, wA2, wA3;               // W set even (16 fp32)
    float4 wB0, wB1, wB2, wB3;               // W set odd

#define PRE_SET(A0, A1, A2, A3, W0, W1, W2, W3, KB) do {                      \
    const float* _ap = x + (size_t)(m0 + srow) * D_MODEL + (KB) + sc * 16;    \
    A0 = *(const float4*)_ap;       A1 = *(const float4*)(_ap + 4);           \
    A2 = *(const float4*)(_ap + 8); A3 = *(const float4*)(_ap + 12);          \
    const float* _wp = W + (size_t)srow * D_MODEL + (KB) + sc * 16;           \
    W0 = *(const float4*)_wp;       W1 = *(const float4*)(_wp + 4);           \
    W2 = *(const float4*)(_wp + 8); W3 = *(const float4*)(_wp + 12);          \
} while (0)

// convert A (x8) and W (x64) fp32 -> fp16 h/l pairs, store swizzled
#define STORE_SET(A0, A1, A2, A3, W0, W1, W2, W3, BB) do {                    \
    _Float16* _Ah = (_Float16*)(smem + (BB) * 32768);                         \
    _Float16* _Al = (_Float16*)(smem + (BB) * 32768 + 8192);                  \
    _Float16* _Wh = (_Float16*)(smem + (BB) * 32768 + 16384);                 \
    _Float16* _Wl = (_Float16*)(smem + (BB) * 32768 + 24576);                 \
    half8 _h0, _l0, _h1, _l1;                                                 \
    CVT1((A0).x * 8.0f, _h0, _l0, 0); CVT1((A0).y * 8.0f, _h0, _l0, 1);       \
    CVT1((A0).z * 8.0f, _h0, _l0, 2); CVT1((A0).w * 8.0f, _h0, _l0, 3);       \
    CVT1((A1).x * 8.0f, _h0, _l0, 4); CVT1((A1).y * 8.0f, _h0, _l0, 5);       \
    CVT1((A1).z * 8.0f, _h0, _l0, 6); CVT1((A1).w * 8.0f, _h0, _l0, 7);       \
    CVT1((A2).x * 8.0f, _h1, _l1, 0); CVT1((A2).y * 8.0f, _h1, _l1, 1);       \
    CVT1((A2).z * 8.0f, _h1, _l1, 2); CVT1((A2).w * 8.0f, _h1, _l1, 3);       \
    CVT1((A3).x * 8.0f, _h1, _l1, 4); CVT1((A3).y * 8.0f, _h1, _l1, 5);       \
    CVT1((A3).z * 8.0f, _h1, _l1, 6); CVT1((A3).w * 8.0f, _h1, _l1, 7);       \
    *(half8*)&_Ah[sof0] = _h0;  *(half8*)&_Ah[sof1] = _h1;                    \
    *(half8*)&_Al[sof0] = _l0;  *(half8*)&_Al[sof1] = _l1;                    \
    half8 _wh0, _wl0, _wh1, _wl1;                                             \
    CVT1((W0).x * 64.0f, _wh0, _wl0, 0); CVT1((W0).y * 64.0f, _wh0, _wl0, 1); \
    CVT1((W0).z * 64.0f, _wh0, _wl0, 2); CVT1((W0).w * 64.0f, _wh0, _wl0, 3); \
    CVT1((W1).x * 64.0f, _wh0, _wl0, 4); CVT1((W1).y * 64.0f, _wh0, _wl0, 5); \
    CVT1((W1).z * 64.0f, _wh0, _wl0, 6); CVT1((W1).w * 64.0f, _wh0, _wl0, 7); \
    CVT1((W2).x * 64.0f, _wh1, _wl1, 0); CVT1((W2).y * 64.0f, _wh1, _wl1, 1); \
    CVT1((W2).z * 64.0f, _wh1, _wl1, 2); CVT1((W2).w * 64.0f, _wh1, _wl1, 3); \
    CVT1((W3).x * 64.0f, _wh1, _wl1, 4); CVT1((W3).y * 64.0f, _wh1, _wl1, 5); \
    CVT1((W3).z * 64.0f, _wh1, _wl1, 6); CVT1((W3).w * 64.0f, _wh1, _wl1, 7); \
    *(half8*)&_Wh[sof0] = _wh0; *(half8*)&_Wh[sof1] = _wh1;                   \
    *(half8*)&_Wl[sof0] = _wl0; *(half8*)&_Wl[sof1] = _wl1;                   \
} while (0)

#define MFMA_PHASE(BB) do {                                                   \
    const _Float16* _Ah = (const _Float16*)(smem + (BB) * 32768);             \
    const _Float16* _Al = (const _Float16*)(smem + (BB) * 32768 + 8192);      \
    const _Float16* _Wh = (const _Float16*)(smem + (BB) * 32768 + 16384);     \
    const _Float16* _Wl = (const _Float16*)(smem + (BB) * 32768 + 24576);     \
    const int arow = wv * 16 + (l & 15);                                      \
    const int rsw  = l & 7;                                                   \
    _Pragma("unroll")                                                         \
    for (int kq = 0; kq < 2; ++kq) {                                          \
        const int s    = kq * 4 + (l >> 4);                                   \
        const int aoff = arow * 64 + ((s ^ rsw) << 3);                        \
        half8 ah = *(const half8*)&_Ah[aoff];                                 \
        half8 al = *(const half8*)&_Al[aoff];                                 \
        _Pragma("unroll")                                                     \
        for (int n = 0; n < 4; ++n) {                                         \
            const int woff = (n * 16 + (l & 15)) * 64 + ((s ^ rsw) << 3);     \
            half8 wh = *(const half8*)&_Wh[woff];                             \
            half8 wl = *(const half8*)&_Wl[woff];                             \
            f32x4 a = (n == 0) ? acc0 : (n == 1) ? acc1 : (n == 2) ? acc2 : acc3; \
            a = __builtin_amdgcn_mfma_f32_16x16x32_f16(al, wl, a, 0, 0, 0);   \
            a = __builtin_amdgcn_mfma_f32_16x16x32_f16(al, wh, a, 0, 0, 0);   \
            a = __builtin_amdgcn_mfma_f32_16x16x32_f16(ah, wl, a, 0, 0, 0);   \
            a = __builtin_amdgcn_mfma_f32_16x16x32_f16(ah, wh, a, 0, 0, 0);   \
            if (n == 0) acc0 = a; else if (n == 1) acc1 = a;                  \
            else if (n == 2) acc2 = a; else acc3 = a;                         \
        }                                                                     \
    }                                                                         \
} while (0)

    f32x4 acc0 = {0.f,0.f,0.f,0.f}, acc1 = {0.f,0.f,0.f,0.f};
    f32x4 acc2 = {0.f,0.f,0.f,0.f}, acc3 = {0.f,0.f,0.f,0.f};

    // prologue: regs for chunks 0,1; store chunk 0 into buf 0
    PRE_SET(aA0, aA1, aA2, aA3, wA0, wA1, wA2, wA3, 0);
    PRE_SET(aB0, aB1, aB2, aB3, wB0, wB1, wB2, wB3, KC);
    STORE_SET(aA0, aA1, aA2, aA3, wA0, wA1, wA2, wA3, 0);
    asm volatile("s_waitcnt lgkmcnt(0)" ::: "memory");
    __builtin_amdgcn_s_barrier();

    for (int ch = 0; ch < NCH; ch += 2) {
        // even chunk: MFMA(buf0) || STORE(setB->buf1) || PRE(setA, ch+2)
        if (ch + 2 < NCH)
            PRE_SET(aA0, aA1, aA2, aA3, wA0, wA1, wA2, wA3, (ch + 2) * KC);
        if (ch + 1 < NCH)
            STORE_SET(aB0, aB1, aB2, aB3, wB0, wB1, wB2, wB3, 1);
        MFMA_PHASE(0);
        asm volatile("s_waitcnt lgkmcnt(0)" ::: "memory");
        __builtin_amdgcn_s_barrier();
        // odd chunk: MFMA(buf1) || STORE(setA->buf0) || PRE(setB, ch+3)
        if (ch + 3 < NCH)
            PRE_SET(aB0, aB1, aB2, aB3, wB0, wB1, wB2, wB3, (ch + 3) * KC);
        if (ch + 2 < NCH)
            STORE_SET(aA0, aA1, aA2, aA3, wA0, wA1, wA2, wA3, 0);
        MFMA_PHASE(1);
        asm volatile("s_waitcnt lgkmcnt(0)" ::: "memory");
        __builtin_amdgcn_s_barrier();
    }

    // ---- stats in-block (r13-proven 256-thr phases; sL aliases LDS) ----
    __syncthreads();                          // all MFMA reads retired
    {
        const int rbase = wv * 16 + (l >> 4) * 4;        // m89 D-layout
        const int col0  = l & 15;
        #pragma unroll
        for (int q = 0; q < 4; ++q) {
            sL[rbase + q][ 0 + col0] = acc0[q] * (1.0f / 512.0f);
            sL[rbase + q][16 + col0] = acc1[q] * (1.0f / 512.0f);
            sL[rbase + q][32 + col0] = acc2[q] * (1.0f / 512.0f);
            sL[rbase + q][48 + col0] = acc3[q] * (1.0f / 512.0f);
        }
    }
    if (t < NE) hist[t] = 0;
    __syncthreads();

    {   // per-quarter argmax (4 threads per token, ascending -> first-max)
        const int m = t >> 2, qr = t & 3;
        float mx = -3.4e38f; int ag = 0;
        #pragma unroll
        for (int k = 0; k < 16; ++k) {
            const int e = qr * 16 + k;
            float v = sL[m][e];
            if (v > mx) { mx = v; ag = e; }
        }
        red4[m][qr] = mx; arg4[m][qr] = ag;
    }
    __syncthreads();
    if (t < 64) {                             // combine ascending: first-max
        const int m = t;
        float mx = red4[m][0]; int ag = arg4[m][0];
        #pragma unroll
        for (int qr = 1; qr < 4; ++qr)
            if (red4[m][qr] > mx) { mx = red4[m][qr]; ag = arg4[m][qr]; }
        smax[m] = mx;
        out[m0 + m] = (float)ag;              // expert_index
        atomicAdd(&hist[ag], 1);
    }
    __syncthreads();
    {   // per-quarter expsum
        const int m = t >> 2, qr = t & 3;
        const float mx = smax[m];
        float s = 0.f;
        #pragma unroll
        for (int k = 0; k < 16; ++k) s += expf(sL[m][qr * 16 + k] - mx);
        red4[m][qr] = s;
    }
    __syncthreads();
    if (t < 64) {
        const int m = t;
        float s = ((red4[m][0] + red4[m][1]) + red4[m][2]) + red4[m][3];
        float inv = 1.f / s;
        sinv[m] = inv;
        out[Ntok + m0 + m] = inv;             // expert_prob
        float lse = smax[m] + logf(s);
        float z = lse * lse;
        #pragma unroll
        for (int off = 32; off > 0; off >>= 1) z += __shfl_down(z, off, 64);
        if (t == 0) ws_z[b] = z;
    }
    __syncthreads();
    {   // probsum: wave mg covers 16 tokens, lane = expert
        const int e = t & 63, mg = t >> 6;
        float pa = 0.f;
        #pragma unroll
        for (int k = 0; k < 16; ++k) {
            const int m = mg * 16 + k;
            pa += expf(sL[m][e] - smax[m]) * sinv[m];
        }
        spart[mg][e] = pa;
    }
    __syncthreads();
    if (t < NE) {
        ws_prob[b * NE + t] = ((spart[0][t] + spart[1][t]) + spart[2][t]) + spart[3][t];
        ws_cnt[b * NE + t]  = hist[t];
    }
}

// ---------------- final reduce (r10/r12-proven) -----------------------------
__global__ __launch_bounds__(256) void router_final2(
    const float* __restrict__ ws_prob, const float* __restrict__ ws_z,
    const int* __restrict__ ws_cnt, float* __restrict__ out,
    int Ntok, int nblocks)
{
    __shared__ float sp[4][NE];
    __shared__ int   sc[4][NE];
    __shared__ float sz[4];

    const int e = threadIdx.x & 63, g = threadIdx.x >> 6;
    const int per = nblocks / 4;
    const int hi  = (g == 3) ? nblocks : (g + 1) * per;

    float ps = 0.f; int c = 0;
    for (int blk = g * per; blk < hi; ++blk) {       // fixed partition
        ps += ws_prob[blk * NE + e];
        c  += ws_cnt[blk * NE + e];
    }
    sp[g][e] = ps; sc[g][e] = c;

    float z = 0.f;
    for (int blk = (int)threadIdx.x; blk < nblocks; blk += 256) z += ws_z[blk];
    #pragma unroll
    for (int off = 32; off > 0; off >>= 1) z += __shfl_down(z, off, 64);
    if (e == 0) sz[g] = z;
    __syncthreads();

    if (threadIdx.x < 64) {
        const int ee = threadIdx.x;
        float pst = ((sp[0][ee] + sp[1][ee]) + sp[2][ee]) + sp[3][ee];
        int   ct  = ((sc[0][ee] + sc[1][ee]) + sc[2][ee]) + sc[3][ee];
        out[2 * Ntok + ee] = (float)ct;              // counts

        float fN = (float)Ntok;
        float fp = ((float)ct / fN) * (pst / fN);
        #pragma unroll
        for (int off = 32; off > 0; off >>= 1) fp += __shfl_down(fp, off, 64);
        if (ee == 0) {
            float zt = ((sz[0] + sz[1]) + sz[2]) + sz[3];
            int cap = (Ntok + NE - 1) / NE;
            if (cap < 4) cap = 4;
            float aux = 0.01f * (float)NE * fp + 1e-3f * (zt / fN);
            out[2 * Ntok + NE]     = (float)cap;     // capacity
            out[2 * Ntok + NE + 1] = aux;            // aux_loss
        }
    }
}

// ---------------- fallback (round-1 proven fused fp32 path) -----------------
__global__ __launch_bounds__(256) void router_main_fb(
    const float* __restrict__ x, const float* __restrict__ W,
    float* __restrict__ out, float* __restrict__ ws_prob,
    float* __restrict__ ws_z, int* __restrict__ ws_cnt, int Ntok)
{
    __shared__ __align__(16) float sX[FB_KC][68];
    __shared__ __align__(16) float sW[FB_KC][68];
    __shared__ float sL[64][65];
    __shared__ float smax[64], sinv[64];
    __shared__ float spart[4][NE];
    __shared__ int   hist[NE];

    const int t = threadIdx.x, b = blockIdx.x, m0 = b * 64;
    const int mq = t & 15, nq = t >> 4;
    const int r1 = t >> 3, r2 = r1 + 32, c1 = (t & 7) << 2;
    const float* xp1 = x + (size_t)(m0 + r1) * D_MODEL + c1;
    const float* xp2 = x + (size_t)(m0 + r2) * D_MODEL + c1;
    const float* wp1 = W + (size_t)r1 * D_MODEL + c1;
    const float* wp2 = W + (size_t)r2 * D_MODEL + c1;
    float4 ax1 = *(const float4*)xp1, ax2 = *(const float4*)xp2;
    float4 aw1 = *(const float4*)wp1, aw2 = *(const float4*)wp2;
    float a1[4][4] = {}, a2[4][4] = {};
    for (int ch = 0; ch < FB_NCH; ++ch) {
        __syncthreads();
        sX[c1+0][r1] = ax1.x; sX[c1+1][r1] = ax1.y; sX[c1+2][r1] = ax1.z; sX[c1+3][r1] = ax1.w;
        sX[c1+0][r2] = ax2.x; sX[c1+1][r2] = ax2.y; sX[c1+2][r2] = ax2.z; sX[c1+3][r2] = ax2.w;
        sW[c1+0][r1] = aw1.x; sW[c1+1][r1] = aw1.y; sW[c1+2][r1] = aw1.z; sW[c1+3][r1] = aw1.w;
        sW[c1+0][r2] = aw2.x; sW[c1+1][r2] = aw2.y; sW[c1+2][r2] = aw2.z; sW[c1+3][r2] = aw2.w;
        __syncthreads();
        if (ch + 1 < FB_NCH) {
            xp1 += FB_KC; xp2 += FB_KC; wp1 += FB_KC; wp2 += FB_KC;
            ax1 = *(const float4*)xp1; ax2 = *(const float4*)xp2;
            aw1 = *(const float4*)wp1; aw2 = *(const float4*)wp2;
        }
        #pragma unroll
        for (int k = 0; k < FB_KC; ++k) {
            float4 xa = *(const float4*)&sX[k][mq << 2];
            float4 wb = *(const float4*)&sW[k][nq << 2];
            float (*A)[4] = (k < FB_KC / 2) ? a1 : a2;
            A[0][0] = fmaf(xa.x, wb.x, A[0][0]); A[0][1] = fmaf(xa.x, wb.y, A[0][1]);
            A[0][2] = fmaf(xa.x, wb.z, A[0][2]); A[0][3] = fmaf(xa.x, wb.w, A[0][3]);
            A[1][0] = fmaf(xa.y, wb.x, A[1][0]); A[1][1] = fmaf(xa.y, wb.y, A[1][1]);
            A[1][2] = fmaf(xa.y, wb.z, A[1][2]); A[1][3] = fmaf(xa.y, wb.w, A[1][3]);
            A[2][0] = fmaf(xa.z, wb.x, A[2][0]); A[2][1] = fmaf(xa.z, wb.y, A[2][1]);
            A[2][2] = fmaf(xa.z, wb.z, A[2][2]); A[2][3] = fmaf(xa.z, wb.w, A[2][3]);
            A[3][0] = fmaf(xa.w, wb.x, A[3][0]); A[3][1] = fmaf(xa.w, wb.y, A[3][1]);
            A[3][2] = fmaf(xa.w, wb.z, A[3][2]); A[3][3] = fmaf(xa.w, wb.w, A[3][3]);
        }
    }
    #pragma unroll
    for (int i = 0; i < 4; ++i)
        #pragma unroll
        for (int j = 0; j < 4; ++j)
            sL[(mq << 2) + i][(nq << 2) + j] = a1[i][j] + a2[i][j];
    if (t < NE) hist[t] = 0;
    __syncthreads();
    if (t < 64) {
        const int m = t;
        float mx = sL[m][0]; int arg = 0;
        for (int e = 1; e < NE; ++e) { float v = sL[m][e]; if (v > mx) { mx = v; arg = e; } }
        float s = 0.f;
        for (int e = 0; e < NE; ++e) s += expf(sL[m][e] - mx);
        float inv = 1.f / s;
        out[m0 + m] = (float)arg; out[Ntok + m0 + m] = inv;
        smax[m] = mx; sinv[m] = inv;
        atomicAdd(&hist[arg], 1);
        float lse = mx + logf(s); float z = lse * lse;
        for (int off = 32; off > 0; off >>= 1) z += __shfl_down(z, off, 64);
        if (t == 0) ws_z[b] = z;
    }
    __syncthreads();
    {
        const int e = t & 63, mg = t >> 6;
        float pa = 0.f;
        for (int m = mg * 16; m < mg * 16 + 16; ++m) pa += expf(sL[m][e] - smax[m]) * sinv[m];
        spart[mg][e] = pa;
    }
    __syncthreads();
    if (t < NE) {
        ws_prob[b * NE + t] = spart[0][t] + spart[1][t] + spart[2][t] + spart[3][t];
        ws_cnt[b * NE + t]  = hist[t];
    }
}

extern "C" void kernel_launch(void* const* d_in, const int* in_sizes, int n_in,
                              void* d_out, int out_size, void* d_ws, size_t ws_size,
                              hipStream_t stream)
{
    const float* x = (const float*)d_in[0];
    const float* W = (const float*)d_in[1];
    float* out = (float*)d_out;

    const int Ntok = in_sizes[0] / D_MODEL;          // 16384
    const int nblk = Ntok / TB;                      // 256

    const size_t need = ((size_t)nblk * NE + nblk) * 4
                      + (size_t)nblk * NE * 4 + 1024;

    if ((Ntok % TB) == 0 && (nblk % 4) == 0 && ws_size >= need) {
        float* ws_prob = (float*)d_ws;
        float* ws_z    = ws_prob + (size_t)nblk * NE;
        int*   ws_cnt  = (int*)(ws_z + nblk);

        router_fused_v2<<<nblk, 256, 0, stream>>>(x, W, out,
                                                  ws_prob, ws_z, ws_cnt, Ntok);
        router_final2<<<1, 256, 0, stream>>>(ws_prob, ws_z, ws_cnt, out, Ntok, nblk);
    } else {
        const int nb = Ntok / 64;
        float* ws_prob = (float*)d_ws;
        float* ws_z    = ws_prob + (size_t)nb * NE;
        int*   ws_cnt  = (int*)(ws_z + nb);
        router_main_fb<<<nb, 256, 0, stream>>>(x, W, out, ws_prob, ws_z, ws_cnt, Ntok);
        router_final2<<<1, 256, 0, stream>>>(ws_prob, ws_z, ws_cnt, out, Ntok, nb);
    }
}